// Round 8
// baseline (270.057 us; speedup 1.0000x reference)
//
#include <hip/hip_runtime.h>
#include <stdint.h>

#define L_SEQ 2048
#define D_MODEL 1024
#define NHEAD 16
#define HS 64
#define B_BATCH 2
// 1/sqrt(64) * log2(e), folded into q at QKV epilogue (softmax in exp2 domain)
#define QSCALE 0.1803368801111243f

typedef __bf16 bf16x8 __attribute__((ext_vector_type(8)));
typedef float f32x4 __attribute__((ext_vector_type(4)));

__device__ __forceinline__ float fexp2(float x) {
  return __builtin_amdgcn_exp2f(x);  // v_exp_f32: D = 2^S0
}

__device__ __forceinline__ unsigned short f2b(float f) {
  unsigned int u = __float_as_uint(f);
  u += 0x7fffu + ((u >> 16) & 1u);
  return (unsigned short)(u >> 16);
}
__device__ __forceinline__ float b2f(unsigned short s) {
  return __uint_as_float(((unsigned int)s) << 16);
}
__device__ __forceinline__ unsigned int pk2(float a, float b) {
  return (unsigned int)f2b(a) | ((unsigned int)f2b(b) << 16);
}

union U8 { uint4 v; unsigned short s[8]; };

// async global->LDS, 16B per lane, dest = wave-uniform base + lane*16
__device__ __forceinline__ void ldsload16(const unsigned short* g, unsigned short* l) {
  __builtin_amdgcn_global_load_lds(
      (const __attribute__((address_space(1))) unsigned int*)g,
      (__attribute__((address_space(3))) unsigned int*)l, 16, 0, 0);
}

// swizzled frag read: rows are 64 shorts (128B) unpadded; 16B unit index is
// XORed with (row&7) so 16 consecutive rows spread over all banks.
__device__ __forceinline__ bf16x8 frag_ld(const unsigned short* base, int row, int ks, int quad) {
  const int unit = (ks * 4 + quad) ^ (row & 7);
  return *(const bf16x8*)(base + row * 64 + unit * 8);
}
// stride-88 variant (wave-private T/P region)
__device__ __forceinline__ bf16x8 frag_ld88(const unsigned short* base, int row, int ks, int quad) {
  const int unit = (ks * 4 + quad) ^ (row & 7);
  return *(const bf16x8*)(base + row * 88 + unit * 8);
}

// -------- prep: all casts/transposes fused into one launch --------
// sections: [0,2048) x | [2048,2116) Er+pad(to L+128 rows) | W_attn^T | W_proj^T
__global__ __launch_bounds__(256) void prep(
    const float* __restrict__ x, const float* __restrict__ Wa,
    const float* __restrict__ Wp, const float* __restrict__ Er,
    unsigned short* __restrict__ xb, unsigned short* __restrict__ wabT,
    unsigned short* __restrict__ wpbT, unsigned short* __restrict__ erb) {
  __shared__ unsigned short tt[64][65];
  int gb = blockIdx.x;
  if (gb < 2048) {  // x: 524288 uint4 elems
    int i = gb * 256 + threadIdx.x;
    const float4* s4 = (const float4*)x;
    float4 a = s4[i * 2], b = s4[i * 2 + 1];
    U8 u;
    u.s[0] = f2b(a.x); u.s[1] = f2b(a.y); u.s[2] = f2b(a.z); u.s[3] = f2b(a.w);
    u.s[4] = f2b(b.x); u.s[5] = f2b(b.y); u.s[6] = f2b(b.z); u.s[7] = f2b(b.w);
    ((uint4*)xb)[i] = u.v;
    return;
  }
  gb -= 2048;
  if (gb < 68) {  // Er: 17408 8-elem groups; groups >= 16384 are zero pad
    int i = gb * 256 + threadIdx.x;
    if (i < 16384) {
      const float4* s4 = (const float4*)Er;
      float4 a = s4[i * 2], b = s4[i * 2 + 1];
      U8 u;
      u.s[0] = f2b(a.x); u.s[1] = f2b(a.y); u.s[2] = f2b(a.z); u.s[3] = f2b(a.w);
      u.s[4] = f2b(b.x); u.s[5] = f2b(b.y); u.s[6] = f2b(b.z); u.s[7] = f2b(b.w);
      ((uint4*)erb)[i] = u.v;
    } else if (i < 17408) {
      ((uint4*)erb)[i] = make_uint4(0u, 0u, 0u, 0u);
    }
    return;
  }
  gb -= 68;
  const float* src;
  unsigned short* dst;
  int N, nbx;
  if (gb < 768) { src = Wa; dst = wabT; N = 3072; nbx = 48; }
  else { gb -= 768; src = Wp; dst = wpbT; N = 1024; nbx = 16; }
  const int n0 = (gb % nbx) * 64, k0 = (gb / nbx) * 64;
  const int c = threadIdx.x & 63, r0 = threadIdx.x >> 6;
#pragma unroll
  for (int i = 0; i < 16; i++) {
    int r = r0 * 16 + i;
    tt[r][c] = f2b(src[(size_t)(k0 + r) * N + n0 + c]);
  }
  __syncthreads();
  const int n = threadIdx.x >> 2, ks = (threadIdx.x & 3) * 16;
  U8 u0, u1;
#pragma unroll
  for (int j = 0; j < 8; j++) {
    u0.s[j] = tt[ks + j][n];
    u1.s[j] = tt[ks + 8 + j][n];
  }
  unsigned short* d = dst + (size_t)(n0 + n) * 1024 + k0 + ks;
  *(uint4*)d = u0.v;
  *(uint4*)(d + 8) = u1.v;
}

// -------- QKV GEMM. q pre-scaled by QSCALE; V stored TRANSPOSED (b,h,d,l)
// via LDS-transposed epilogue (coalesced 256B segments along l).
__global__ __launch_bounds__(256, 3) void gemm_qkv(
    const unsigned short* __restrict__ A, const unsigned short* __restrict__ Bt,
    const float* __restrict__ bias, unsigned short* __restrict__ qbuf,
    unsigned short* __restrict__ kbuf, unsigned short* __restrict__ vbufT,
    int M, int N, int K) {
  __shared__ unsigned short SMEM[2 * 128 * 64];  // As | Bs; reused as Vs[128][128]
  unsigned short* As = SMEM;
  unsigned short* Bs = SMEM + 128 * 64;
  const int tid = threadIdx.x, lane = tid & 63, w = tid >> 6;
  const int wm = w >> 1, wn = w & 1, quad = lane >> 4, lc = lane & 15;
  const int bm = blockIdx.y, bn = blockIdx.x;
  const int l8 = lane >> 3, u8 = ((lane & 7) ^ l8) * 8;
  const unsigned short* Ab = A + (size_t)bm * 128 * K;
  const unsigned short* Bb = Bt + (size_t)bn * 128 * K;

  f32x4 z4 = {0.f, 0.f, 0.f, 0.f};
  f32x4 acc[4][4];
#pragma unroll
  for (int mb = 0; mb < 4; mb++)
#pragma unroll
    for (int nb = 0; nb < 4; nb++) acc[mb][nb] = z4;

  for (int kk = 0; kk < K; kk += 64) {
    if (kk) __syncthreads();
#pragma unroll
    for (int i = 0; i < 4; i++) {
      int ch = w * 4 + i;
      ldsload16(Ab + (size_t)(ch * 8 + l8) * K + kk + u8, &As[ch * 512]);
      ldsload16(Bb + (size_t)(ch * 8 + l8) * K + kk + u8, &Bs[ch * 512]);
    }
    __syncthreads();
#pragma unroll
    for (int ks = 0; ks < 2; ks++) {
      bf16x8 af[4], bfv[4];
#pragma unroll
      for (int mb = 0; mb < 4; mb++) af[mb] = frag_ld(As, wm * 64 + mb * 16 + lc, ks, quad);
#pragma unroll
      for (int nb = 0; nb < 4; nb++) bfv[nb] = frag_ld(Bs, wn * 64 + nb * 16 + lc, ks, quad);
#pragma unroll
      for (int mb = 0; mb < 4; mb++)
#pragma unroll
        for (int nb = 0; nb < 4; nb++)
          acc[mb][nb] = __builtin_amdgcn_mfma_f32_16x16x32_bf16(af[mb], bfv[nb],
                                                               acc[mb][nb], 0, 0, 0);
    }
  }

  if (bn < 16) {
    // q/k blocks
#pragma unroll
    for (int nb = 0; nb < 4; nb++) {
      const int n = bn * 128 + wn * 64 + nb * 16 + lc;
      const float bv = bias[n];
      const int which = n >> 10;
      const int rem = n & 1023;
      const int h = rem >> 6, d = rem & 63;
      unsigned short* dst = which == 0 ? qbuf : kbuf;
      const float sc = which == 0 ? QSCALE : 1.0f;
#pragma unroll
      for (int mb = 0; mb < 4; mb++) {
#pragma unroll
        for (int reg = 0; reg < 4; reg++) {
          const int m = bm * 128 + wm * 64 + mb * 16 + quad * 4 + reg;
          const int b = m >> 11, l = m & 2047;
          float val = (acc[mb][nb][reg] + bv) * sc;
          dst[((size_t)(b * NHEAD + h) * L_SEQ + l) * HS + d] = f2b(val);
        }
      }
    }
  } else {
    // v blocks: LDS transpose -> coalesced stores along l into (b,h,d,l).
    __syncthreads();  // all frag reads of As/Bs done
    unsigned short* Vs = SMEM;  // [n 128][m 128], XOR-swizzled 8-short units
#pragma unroll
    for (int nb = 0; nb < 4; nb++) {
      const int n_loc = wn * 64 + nb * 16 + lc;
      const float bv = bias[bn * 128 + n_loc];
#pragma unroll
      for (int mb = 0; mb < 4; mb++) {
#pragma unroll
        for (int reg = 0; reg < 4; reg++) {
          const int m_loc = wm * 64 + mb * 16 + quad * 4 + reg;
          Vs[n_loc * 128 + (((m_loc >> 3) ^ (n_loc & 15)) << 3) + (m_loc & 7)] =
              f2b(acc[mb][nb][reg] + bv);
        }
      }
    }
    __syncthreads();
    const int n_loc = tid >> 1, mh = tid & 1;
    const int n_glob = bn * 128 + n_loc;
    const int rem = n_glob & 1023;
    const int h = rem >> 6, d = rem & 63;
    const int b = bm >> 4;
    // l = m & 2047 = (bm & 15) * 128 + m_loc
    unsigned short* dstb =
        vbufT + ((size_t)(b * NHEAD + h) * HS + d) * L_SEQ + (bm & 15) * 128;
#pragma unroll
    for (int c = 0; c < 8; c++) {
      const int cg = mh * 8 + c;
      const int u = cg ^ (n_loc & 15);
      *(uint4*)(dstb + cg * 8) = *(const uint4*)&Vs[n_loc * 128 + u * 8];
    }
  }
}

// -------- proj GEMM: 128Mx64N tile -> 512 blocks (2/CU), f32 out --------
__global__ __launch_bounds__(256, 2) void gemm_proj(
    const unsigned short* __restrict__ A, const unsigned short* __restrict__ Bt,
    const float* __restrict__ bias, float* __restrict__ out, int M, int N, int K) {
  __shared__ unsigned short As[128 * 64];
  __shared__ unsigned short Bs[64 * 64];
  const int tid = threadIdx.x, lane = tid & 63, w = tid >> 6;
  const int quad = lane >> 4, lc = lane & 15;
  const int bm = blockIdx.y, bn = blockIdx.x;
  const int l8 = lane >> 3, u8 = ((lane & 7) ^ l8) * 8;
  const unsigned short* Ab = A + (size_t)bm * 128 * K;
  const unsigned short* Bb = Bt + (size_t)bn * 64 * K;

  f32x4 z4 = {0.f, 0.f, 0.f, 0.f};
  f32x4 acc[2][4];
#pragma unroll
  for (int mb = 0; mb < 2; mb++)
#pragma unroll
    for (int nb = 0; nb < 4; nb++) acc[mb][nb] = z4;

  for (int kk = 0; kk < K; kk += 64) {
    if (kk) __syncthreads();
#pragma unroll
    for (int i = 0; i < 4; i++) {
      int ch = w * 4 + i;
      ldsload16(Ab + (size_t)(ch * 8 + l8) * K + kk + u8, &As[ch * 512]);
    }
#pragma unroll
    for (int i = 0; i < 2; i++) {
      int ch = w * 2 + i;
      ldsload16(Bb + (size_t)(ch * 8 + l8) * K + kk + u8, &Bs[ch * 512]);
    }
    __syncthreads();
#pragma unroll
    for (int ks = 0; ks < 2; ks++) {
      bf16x8 af[2], bfv[4];
#pragma unroll
      for (int mb = 0; mb < 2; mb++) af[mb] = frag_ld(As, w * 32 + mb * 16 + lc, ks, quad);
#pragma unroll
      for (int nb = 0; nb < 4; nb++) bfv[nb] = frag_ld(Bs, nb * 16 + lc, ks, quad);
#pragma unroll
      for (int mb = 0; mb < 2; mb++)
#pragma unroll
        for (int nb = 0; nb < 4; nb++)
          acc[mb][nb] = __builtin_amdgcn_mfma_f32_16x16x32_bf16(af[mb], bfv[nb],
                                                               acc[mb][nb], 0, 0, 0);
    }
  }

#pragma unroll
  for (int nb = 0; nb < 4; nb++) {
    const int n = bn * 64 + nb * 16 + lc;
    const float bv = bias[n];
#pragma unroll
    for (int mb = 0; mb < 2; mb++) {
#pragma unroll
      for (int reg = 0; reg < 4; reg++) {
        const int m = bm * 128 + w * 32 + mb * 16 + quad * 4 + reg;
        out[(size_t)m * N + n] = acc[mb][nb][reg] + bv;
      }
    }
  }
}

// -------- flash attention, transposed-S, PAIRED adjacent q-tiles --------
// Block owns q-tiles (2p, 2p+1); one k-loop serves both: K/V staged once and
// their register fragments reused for both tiles; Er staged as one 192-row
// band containing both windows. Single-buffer 2-barrier structure (round-5).
// p = exp2(s+t), no online max (scores bounded). LDS 52224B -> 3 blocks/CU.
__global__ __launch_bounds__(256, 3) void flash_attn_rel(
    const unsigned short* __restrict__ qb, const unsigned short* __restrict__ kb,
    const unsigned short* __restrict__ vbT, const unsigned short* __restrict__ erb,
    unsigned short* __restrict__ yb) {
  __shared__ unsigned short Ks[64 * 64];
  __shared__ unsigned short Vt[64 * 64];
  __shared__ unsigned short Es[192 * 64];     // 192-row Er band
  __shared__ unsigned short TP[4 * 16 * 88];  // wave-private T/P; epilogue Yt[64][72]

  const int tid = threadIdx.x, lane = tid & 63, w = tid >> 6;
  const int quad = lane >> 4, lc = lane & 15;
  const int bh = blockIdx.x;
  const int b = bh >> 4, h = bh & 15;
  const int p = 15 - (int)blockIdx.y;  // longest pair first
  const int q0lo = 2 * p * 64, q0hi = q0lo + 64;
  const size_t hoff = (size_t)bh * L_SEQ * HS;
  unsigned short* TPw = TP + w * (16 * 88);
  const int l8 = lane >> 3, u8 = ((lane & 7) ^ l8) * 8;
  const f32x4 z4 = {0.f, 0.f, 0.f, 0.f};
  const unsigned short* kgb = kb + hoff;
  const unsigned short* vgbT = vbT + hoff;

  // Q fragments for both tiles (q pre-scaled by QSCALE at QKV epilogue)
  bf16x8 qfh[2], qfl[2];
  {
    const unsigned short* qh = qb + hoff + (size_t)(q0hi + w * 16 + lc) * HS;
    const unsigned short* ql = qb + hoff + (size_t)(q0lo + w * 16 + lc) * HS;
    qfh[0] = *(const bf16x8*)(qh + quad * 8);
    qfh[1] = *(const bf16x8*)(qh + 32 + quad * 8);
    qfl[0] = *(const bf16x8*)(ql + quad * 8);
    qfl[1] = *(const bf16x8*)(ql + 32 + quad * 8);
  }
  f32x4 Oh[4], Ol[4];
#pragma unroll
  for (int db = 0; db < 4; db++) { Oh[db] = z4; Ol[db] = z4; }
  float psh = 0.0f, psl = 0.0f;

  // per-tile softmax + PV (T already in tacc; V frags in vf)
  auto softmax_pv = [&](f32x4 (&sacc)[4], f32x4 (&tacc)[5], bool diag,
                        float& psum_acc, f32x4 (&Oacc)[4], bf16x8 (&vf)[2][4]) {
#pragma unroll
    for (int eb = 0; eb < 5; eb++) {
      uint2 pk;
      pk.x = pk2(tacc[eb][0], tacc[eb][1]);
      pk.y = pk2(tacc[eb][2], tacc[eb][3]);
      *(uint2*)&TPw[lc * 88 + eb * 16 + quad * 4] = pk;
    }
    asm volatile("" ::: "memory");
    float pv[4][4], ps = 0.0f;
    const int tbase = lc * 88 + (15 - lc);
    if (diag) {
      const int qrow = w * 16 + lc;
#pragma unroll
      for (int kbi = 0; kbi < 4; kbi++)
#pragma unroll
        for (int reg = 0; reg < 4; reg++) {
          const int kk = kbi * 16 + quad * 4 + reg;
          float t = b2f(TPw[tbase + kk]);
          float v = (kk > qrow) ? -1e30f : (sacc[kbi][reg] + t);
          pv[kbi][reg] = fexp2(v);
          ps += pv[kbi][reg];
        }
    } else {
#pragma unroll
      for (int kbi = 0; kbi < 4; kbi++)
#pragma unroll
        for (int reg = 0; reg < 4; reg++) {
          float t = b2f(TPw[tbase + kbi * 16 + quad * 4 + reg]);
          pv[kbi][reg] = fexp2(sacc[kbi][reg] + t);
          ps += pv[kbi][reg];
        }
    }
    psum_acc += ps;
#pragma unroll
    for (int kbi = 0; kbi < 4; kbi++) {
      uint2 pk;
      pk.x = pk2(pv[kbi][0], pv[kbi][1]);
      pk.y = pk2(pv[kbi][2], pv[kbi][3]);
      const int kk2 = kbi * 16 + quad * 4;
      *(uint2*)&TPw[lc * 88 + (((kk2 >> 3) ^ (lc & 7)) << 3) + (kk2 & 7)] = pk;
    }
    asm volatile("" ::: "memory");
#pragma unroll
    for (int ks = 0; ks < 2; ks++) {
      bf16x8 pf = frag_ld88(TPw, lc, ks, quad);
#pragma unroll
      for (int db = 0; db < 4; db++)
        Oacc[db] = __builtin_amdgcn_mfma_f32_16x16x32_bf16(vf[ks][db], pf, Oacc[db], 0, 0, 0);
    }
  };

#pragma unroll 1
  for (int k0 = 0; k0 <= q0hi; k0 += 64) {
    const bool lo_active = (k0 <= q0lo);
    __syncthreads();  // prior-iter LDS reads complete
    // --- stage K, V^T, 192-row Er band ---
#pragma unroll
    for (int i = 0; i < 2; i++) {
      int ch = w * 2 + i;
      ldsload16(kgb + (size_t)(k0 + ch * 8 + l8) * HS + u8, &Ks[ch * 512]);
      ldsload16(vgbT + (size_t)(ch * 8 + l8) * L_SEQ + k0 + u8, &Vt[ch * 512]);
    }
    const int e0 = (L_SEQ - 64) - q0hi + k0;  // >=0; max row e0+191 <= L+127 (padded)
#pragma unroll
    for (int i = 0; i < 6; i++) {
      int ch = w * 6 + i;
      ldsload16(erb + (size_t)(e0 + ch * 8 + l8) * HS + u8, &Es[ch * 512]);
    }
    __syncthreads();

    // --- S^T for both tiles, sharing K fragments ---
    f32x4 sh[4], sl[4];
#pragma unroll
    for (int i = 0; i < 4; i++) { sh[i] = z4; sl[i] = z4; }
#pragma unroll
    for (int ks = 0; ks < 2; ks++) {
      bf16x8 kf[4];
#pragma unroll
      for (int kbi = 0; kbi < 4; kbi++) kf[kbi] = frag_ld(Ks, kbi * 16 + lc, ks, quad);
#pragma unroll
      for (int kbi = 0; kbi < 4; kbi++)
        sh[kbi] = __builtin_amdgcn_mfma_f32_16x16x32_bf16(kf[kbi], qfh[ks], sh[kbi], 0, 0, 0);
      if (lo_active) {
#pragma unroll
        for (int kbi = 0; kbi < 4; kbi++)
          sl[kbi] = __builtin_amdgcn_mfma_f32_16x16x32_bf16(kf[kbi], qfl[ks], sl[kbi], 0, 0, 0);
      }
    }

    // --- hi tile: T^T, softmax, PV (V frags loaded once, kept for lo) ---
    f32x4 th[5];
#pragma unroll
    for (int i = 0; i < 5; i++) th[i] = z4;
    const int rsh = 48 - w * 16;  // hi window start within Es
#pragma unroll
    for (int ks = 0; ks < 2; ks++)
#pragma unroll
      for (int eb = 0; eb < 5; eb++)
        th[eb] = __builtin_amdgcn_mfma_f32_16x16x32_bf16(
            frag_ld(Es, rsh + eb * 16 + lc, ks, quad), qfh[ks], th[eb], 0, 0, 0);

    bf16x8 vf[2][4];
#pragma unroll
    for (int ks = 0; ks < 2; ks++)
#pragma unroll
      for (int db = 0; db < 4; db++) vf[ks][db] = frag_ld(Vt, db * 16 + lc, ks, quad);

    softmax_pv(sh, th, k0 == q0hi, psh, Oh, vf);

    // --- lo tile (reuses V frags; TP reuse safe: per-wave DS ops are in-order) ---
    if (lo_active) {
      f32x4 tl[5];
#pragma unroll
      for (int i = 0; i < 5; i++) tl[i] = z4;
      const int rsl = 112 - w * 16;  // lo window start within Es
#pragma unroll
      for (int ks = 0; ks < 2; ks++)
#pragma unroll
        for (int eb = 0; eb < 5; eb++)
          tl[eb] = __builtin_amdgcn_mfma_f32_16x16x32_bf16(
              frag_ld(Es, rsl + eb * 16 + lc, ks, quad), qfl[ks], tl[eb], 0, 0, 0);
      softmax_pv(sl, tl, k0 == q0lo, psl, Ol, vf);
    }
  }

  // --- reductions ---
  psh += __shfl_xor(psh, 16, 64);
  psh += __shfl_xor(psh, 32, 64);
  psl += __shfl_xor(psl, 16, 64);
  psl += __shfl_xor(psl, 32, 64);
  const float invh = 1.0f / psh, invl = 1.0f / psl;

  // --- epilogue per tile: O^T/l -> LDS transpose -> coalesced store ---
  unsigned short* Yt = TP;  // [64][72]
#pragma unroll 1
  for (int t = 0; t < 2; t++) {
    const float inv = t == 0 ? invh : invl;
    const int q0 = t == 0 ? q0hi : q0lo;
    f32x4* O = t == 0 ? Oh : Ol;
    __syncthreads();
#pragma unroll
    for (int db = 0; db < 4; db++) {
      uint2 pk;
      pk.x = pk2(O[db][0] * inv, O[db][1] * inv);
      pk.y = pk2(O[db][2] * inv, O[db][3] * inv);
      *(uint2*)&Yt[(w * 16 + lc) * 72 + db * 16 + quad * 4] = pk;
    }
    __syncthreads();
    const int r = tid >> 2, seg = (tid & 3) * 16;
    uint4 a0 = *(const uint4*)&Yt[r * 72 + seg];
    uint4 a1 = *(const uint4*)&Yt[r * 72 + seg + 8];
    unsigned short* d = yb + (size_t)((size_t)b * L_SEQ + q0 + r) * D_MODEL + h * HS + seg;
    *(uint4*)d = a0;
    *(uint4*)(d + 8) = a1;
  }
}

extern "C" void kernel_launch(void* const* d_in, const int* in_sizes, int n_in,
                              void* d_out, int out_size, void* d_ws, size_t ws_size,
                              hipStream_t stream) {
  const float* x = (const float*)d_in[0];
  const float* W_attn = (const float*)d_in[1];
  const float* b_attn = (const float*)d_in[2];
  const float* W_proj = (const float*)d_in[3];
  const float* b_proj = (const float*)d_in[4];
  const float* Er = (const float*)d_in[5];
  float* out = (float*)d_out;

  const int n_x = B_BATCH * L_SEQ * D_MODEL;        // 4,194,304
  const int n_wa = D_MODEL * 3 * D_MODEL;           // 3,145,728
  const int n_wp = D_MODEL * D_MODEL;               // 1,048,576
  const int n_er_pad = (L_SEQ + 128) * HS;          // 139,264 (128 zero rows)
  const int n_head = B_BATCH * NHEAD * L_SEQ * HS;  // 4,194,304

  unsigned short* xb = (unsigned short*)d_ws;
  unsigned short* wabT = xb + n_x;     // W_attn^T (3072 x 1024) bf16
  unsigned short* wpbT = wabT + n_wa;  // W_proj^T (1024 x 1024) bf16
  unsigned short* erb = wpbT + n_wp;
  unsigned short* qbuf = erb + n_er_pad;
  unsigned short* kbuf = qbuf + n_head;
  unsigned short* vbufT = kbuf + n_head;  // V^T per head: (b,h,d,l)
  unsigned short* ybuf = vbufT + n_head;  // (B*L, D) bf16

  prep<<<3140, 256, 0, stream>>>(x, W_attn, W_proj, Er, xb, wabT, wpbT, erb);

  gemm_qkv<<<dim3(24, 32), 256, 0, stream>>>(xb, wabT, b_attn, qbuf, kbuf, vbufT,
                                             B_BATCH * L_SEQ, 3 * D_MODEL, D_MODEL);

  flash_attn_rel<<<dim3(B_BATCH * NHEAD, 16), 256, 0, stream>>>(qbuf, kbuf, vbufT,
                                                                erb, ybuf);

  gemm_proj<<<dim3(16, 32), 256, 0, stream>>>(ybuf, wpbT, b_proj, out,
                                              B_BATCH * L_SEQ, D_MODEL, D_MODEL);
}